// Round 3
// baseline (82.507 us; speedup 1.0000x reference)
//
#include <hip/hip_runtime.h>
#include <hip/hip_bf16.h>

// Problem constants (fixed by setup_inputs)
#define NB 8
#define G  2048
#define C  512
#define CH 8
#define NM 4
#define HD 10
#define NS 10
#define L1 1022   // (2048-5)/2+1
#define L2 509    // (1022-5)/2+1
#define L3 253    // (509-5)/2+1
#define L4 125    // (253-5)/2+1

// ---------------- Kernel 1: RBF density + datarepr -> f32 d_out ----------------
// grid: NB*64 blocks of 256 threads; each block: one b, 32 g's (thread = (g_local, H))
__global__ __launch_bounds__(256) void k_density(
    const float* __restrict__ xc, const float* __restrict__ yc,
    const float* __restrict__ xg, const float* __restrict__ logls,
    float* __restrict__ out_den,   // d_out + 0       (nb,G,ch)
    float* __restrict__ out_rep)   // d_out + 131072  (nb,G,ch)
{
    __shared__ float sxc[C * CH];
    __shared__ float syc[C * CH];
    const int b   = blockIdx.x >> 6;   // 64 g-tiles per b
    const int gt  = blockIdx.x & 63;
    const int tid = threadIdx.x;

    const float4* xcb = (const float4*)(xc + b * C * CH);
    const float4* ycb = (const float4*)(yc + b * C * CH);
    for (int i = tid; i < (C * CH) / 4; i += 256) {
        ((float4*)sxc)[i] = xcb[i];
        ((float4*)syc)[i] = ycb[i];
    }
    __syncthreads();

    const int H  = tid & 7;
    const int gl = tid >> 3;          // 0..31
    const int g  = gt * 32 + gl;

    const float x    = xg[(b * G + g) * CH + H];
    const float coef = -0.5f * __expf(-2.0f * logls[H]);   // -0.5 / ls^2

    float den = 0.0f, num = 0.0f;
    for (int c = 0; c < C; ++c) {
        const float d = x - sxc[c * CH + H];
        const float w = __expf(coef * d * d);
        den += w;
        num = fmaf(w, syc[c * CH + H], num);
    }
    const int oidx = (b * G + g) * CH + H;
    out_den[oidx] = den;
    out_rep[oidx] = num / (den + 1e-4f);
}

// ---------------- Kernel 2: fused conv1..4 + pool + linear + softmax + gumbel ----
// one block per b, 256 threads; all intermediates in LDS (~61 KB)
__global__ __launch_bounds__(256) void k_net(
    const float* __restrict__ rep,   // d_out + 131072, layout (b,g,ch)
    const float* __restrict__ w1, const float* __restrict__ b1,
    const float* __restrict__ w2, const float* __restrict__ b2,
    const float* __restrict__ w3, const float* __restrict__ b3,
    const float* __restrict__ w4, const float* __restrict__ b4,
    const float* __restrict__ wl, const float* __restrict__ bl,
    const float* __restrict__ unif,
    float* __restrict__ out_mw,   // d_out + 262144 : (NB, CH, NM)
    float* __restrict__ out_ms)   // d_out + 262400 : (NB, NS, CH, NM)
{
    __shared__ float P[HD * L1];   // h1, later reused for h3
    __shared__ float Q[HD * L2];   // h2, later reused for h4
    __shared__ float hm[HD];
    __shared__ float lg[CH * NM];
    __shared__ float ltt[CH * NM];
    const int b   = blockIdx.x;
    const int tid = threadIdx.x;
    const float* repb = rep + b * G * CH;   // rep[g*CH + c]

    // conv1: x[c][g] = rep^T, read straight from global (L2-resident)
    for (int i = tid; i < HD * L1; i += 256) {
        const int l = i % L1, o = i / L1;
        float acc = b1[o];
        for (int ci = 0; ci < CH; ++ci)
            #pragma unroll
            for (int k = 0; k < 5; ++k)
                acc = fmaf(repb[(2 * l + k) * CH + ci], w1[(o * CH + ci) * 5 + k], acc);
        P[i] = fmaxf(acc, 0.0f);
    }
    __syncthreads();

    // conv2: P(h1) -> Q(h2)
    for (int i = tid; i < HD * L2; i += 256) {
        const int l = i % L2, o = i / L2;
        float acc = b2[o];
        for (int ci = 0; ci < HD; ++ci)
            #pragma unroll
            for (int k = 0; k < 5; ++k)
                acc = fmaf(P[ci * L1 + 2 * l + k], w2[(o * HD + ci) * 5 + k], acc);
        Q[i] = fmaxf(acc, 0.0f);
    }
    __syncthreads();

    // conv3: Q(h2) -> P(h3)   (h1 is dead)
    for (int i = tid; i < HD * L3; i += 256) {
        const int l = i % L3, o = i / L3;
        float acc = b3[o];
        for (int ci = 0; ci < HD; ++ci)
            #pragma unroll
            for (int k = 0; k < 5; ++k)
                acc = fmaf(Q[ci * L2 + 2 * l + k], w3[(o * HD + ci) * 5 + k], acc);
        P[i] = fmaxf(acc, 0.0f);
    }
    __syncthreads();

    // conv4 (no relu): P(h3) -> Q(h4)   (h2 is dead)
    for (int i = tid; i < HD * L4; i += 256) {
        const int l = i % L4, o = i / L4;
        float acc = b4[o];
        for (int ci = 0; ci < HD; ++ci)
            #pragma unroll
            for (int k = 0; k < 5; ++k)
                acc = fmaf(P[ci * L3 + 2 * l + k], w4[(o * HD + ci) * 5 + k], acc);
        Q[i] = acc;
    }
    __syncthreads();

    // adaptive avg pool -> hm[HD]
    if (tid < HD) {
        float s = 0.0f;
        for (int l = 0; l < L4; ++l) s += Q[tid * L4 + l];
        hm[tid] = s * (1.0f / (float)L4);
    }
    __syncthreads();

    // linear -> 32 raw logits
    if (tid < CH * NM) {
        float acc = bl[tid];
        #pragma unroll
        for (int k = 0; k < HD; ++k) acc = fmaf(wl[tid * HD + k], hm[k], acc);
        lg[tid] = acc;
    }
    __syncthreads();

    // tempered logits + mixweight softmax (per channel)
    if (tid < CH) {
        float lv[NM];
        #pragma unroll
        for (int m = 0; m < NM; ++m) lv[m] = lg[tid * NM + m];
        const float m0 = fmaxf(fmaxf(lv[0], lv[1]), fmaxf(lv[2], lv[3]));
        float e[NM], s = 0.0f;
        #pragma unroll
        for (int m = 0; m < NM; ++m) {
            const float v = (lv[m] - m0) / 0.1f;
            ltt[tid * NM + m] = v;
            e[m] = __expf(v);
            s += e[m];
        }
        #pragma unroll
        for (int m = 0; m < NM; ++m)
            out_mw[(b * CH + tid) * NM + m] = e[m] / s;
    }
    __syncthreads();

    // gumbel-softmax samples: NS*CH = 80 (s, ch) pairs
    for (int i = tid; i < NS * CH; i += 256) {
        const int c = i % CH, sI = i / CH;
        const float* up = unif + ((b * NS + sI) * CH + c) * NM;
        float hh[NM], mx = -1e30f;
        #pragma unroll
        for (int m = 0; m < NM; ++m) {
            const float gu = -__logf(-__logf(up[m] + 1e-8f));
            hh[m] = (gu + ltt[c * NM + m]) / 0.1f;
            mx = fmaxf(mx, hh[m]);
        }
        float e2[NM], ss = 0.0f;
        #pragma unroll
        for (int m = 0; m < NM; ++m) { e2[m] = __expf(hh[m] - mx); ss += e2[m]; }
        #pragma unroll
        for (int m = 0; m < NM; ++m) {
            float y = e2[m] / ss;
            y = fminf(fmaxf(y, 1e-8f), 1.0f - 1e-8f);
            out_ms[((b * NS + sI) * CH + c) * NM + m] = y;
        }
    }
}

extern "C" void kernel_launch(void* const* d_in, const int* in_sizes, int n_in,
                              void* d_out, int out_size, void* d_ws, size_t ws_size,
                              hipStream_t stream) {
    const float* xc    = (const float*)d_in[0];
    const float* yc    = (const float*)d_in[1];
    const float* xg    = (const float*)d_in[2];
    const float* logls = (const float*)d_in[3];
    const float* w1    = (const float*)d_in[4];
    const float* b1    = (const float*)d_in[5];
    const float* w2    = (const float*)d_in[6];
    const float* b2    = (const float*)d_in[7];
    const float* w3    = (const float*)d_in[8];
    const float* b3    = (const float*)d_in[9];
    const float* w4    = (const float*)d_in[10];
    const float* b4    = (const float*)d_in[11];
    const float* wl    = (const float*)d_in[12];
    const float* bl    = (const float*)d_in[13];
    const float* unif  = (const float*)d_in[14];

    float* out = (float*)d_out;                 // reference outputs are float32
    float* out_den = out;                       // 131072
    float* out_rep = out + NB * G * CH;         // 131072
    float* out_mw  = out + 2 * NB * G * CH;     // 256
    float* out_ms  = out_mw + NB * CH * NM;     // 2560
    (void)d_ws; (void)ws_size; (void)out_size; (void)in_sizes; (void)n_in;

    k_density<<<NB * 64, 256, 0, stream>>>(xc, yc, xg, logls, out_den, out_rep);

    k_net<<<NB, 256, 0, stream>>>(out_rep, w1, b1, w2, b2, w3, b3, w4, b4,
                                  wl, bl, unif, out_mw, out_ms);
}

// Round 4
// 38.470 us; speedup vs baseline: 2.1447x; 2.1447x over previous
//
#include <hip/hip_runtime.h>
#include <hip/hip_bf16.h>

// Problem constants (fixed by setup_inputs)
#define NB 8
#define G  2048
#define C  512
#define CH 8
#define NM 4
#define HD 10
#define NS 10
#define L1 1022   // (2048-5)/2+1
#define L2 509    // (1022-5)/2+1
#define L3 253    // (509-5)/2+1
#define L4 125    // (253-5)/2+1

// ---------------- Kernel 1: RBF density + datarepr -> f32 d_out ----------------
__global__ __launch_bounds__(256) void k_density(
    const float* __restrict__ xc, const float* __restrict__ yc,
    const float* __restrict__ xg, const float* __restrict__ logls,
    float* __restrict__ out_den,   // d_out + 0       (nb,G,ch)
    float* __restrict__ out_rep)   // d_out + 131072  (nb,G,ch)
{
    __shared__ float sxc[C * CH];
    __shared__ float syc[C * CH];
    const int b   = blockIdx.x >> 6;   // 64 g-tiles per b
    const int gt  = blockIdx.x & 63;
    const int tid = threadIdx.x;

    const float4* xcb = (const float4*)(xc + b * C * CH);
    const float4* ycb = (const float4*)(yc + b * C * CH);
    for (int i = tid; i < (C * CH) / 4; i += 256) {
        ((float4*)sxc)[i] = xcb[i];
        ((float4*)syc)[i] = ycb[i];
    }
    __syncthreads();

    const int H  = tid & 7;
    const int gl = tid >> 3;          // 0..31
    const int g  = gt * 32 + gl;

    const float x    = xg[(b * G + g) * CH + H];
    const float coef = -0.5f * __expf(-2.0f * logls[H]);   // -0.5 / ls^2

    float den = 0.0f, num = 0.0f;
    for (int c = 0; c < C; ++c) {
        const float d = x - sxc[c * CH + H];
        const float w = __expf(coef * d * d);
        den += w;
        num = fmaf(w, syc[c * CH + H], num);
    }
    const int oidx = (b * G + g) * CH + H;
    out_den[oidx] = den;
    out_rep[oidx] = num / (den + 1e-4f);
}

// ---------------- conv1: rep (b,g,ch) -> h1 (b,o,l1), relu ----------------
__global__ __launch_bounds__(256) void k_conv1(
    const float* __restrict__ rep, const float* __restrict__ w1,
    const float* __restrict__ b1, float* __restrict__ h1)
{
    const int idx = blockIdx.x * 256 + threadIdx.x;
    if (idx >= NB * HD * L1) return;
    const int l = idx % L1;
    const int t = idx / L1;
    const int o = t % HD;
    const int b = t / HD;

    const float* ip = rep + (b * G + 2 * l) * CH;
    const float* wp = w1 + o * CH * 5;
    float acc = b1[o];
    #pragma unroll
    for (int k = 0; k < 5; ++k)
        #pragma unroll
        for (int ci = 0; ci < CH; ++ci)
            acc = fmaf(ip[k * CH + ci], wp[ci * 5 + k], acc);
    h1[(b * HD + o) * L1 + l] = fmaxf(acc, 0.0f);
}

// ---------------- generic conv (b,cin,lin) -> (b,o,lout), relu ----------------
template<int CIN, int LIN, int LOUT>
__global__ __launch_bounds__(256) void k_conv(
    const float* __restrict__ in, const float* __restrict__ w,
    const float* __restrict__ bias, float* __restrict__ out)
{
    const int idx = blockIdx.x * 256 + threadIdx.x;
    if (idx >= NB * HD * LOUT) return;
    const int l = idx % LOUT;
    const int t = idx / LOUT;
    const int o = t % HD;
    const int b = t / HD;

    const float* ip = in + (b * CIN) * LIN + 2 * l;
    const float* wp = w + o * CIN * 5;
    float acc = bias[o];
    #pragma unroll
    for (int ci = 0; ci < CIN; ++ci)
        #pragma unroll
        for (int k = 0; k < 5; ++k)
            acc = fmaf(ip[ci * LIN + k], wp[ci * 5 + k], acc);
    out[(b * HD + o) * LOUT + l] = fmaxf(acc, 0.0f);
}

// ---------------- head: conv4 + pool + linear + softmax + gumbel ----------------
__global__ __launch_bounds__(256) void k_head(
    const float* __restrict__ h3,   // (NB, HD, L3)
    const float* __restrict__ w4, const float* __restrict__ b4,
    const float* __restrict__ wl, const float* __restrict__ bl,
    const float* __restrict__ unif,
    float* __restrict__ out_mw,   // (NB, CH, NM)
    float* __restrict__ out_ms)   // (NB, NS, CH, NM)
{
    __shared__ float sh4[HD * L4];
    __shared__ float hm[HD];
    __shared__ float ltt[CH * NM];
    const int b   = blockIdx.x;
    const int tid = threadIdx.x;

    // conv4 (no relu): 1250 outputs
    for (int i = tid; i < HD * L4; i += 256) {
        const int l = i % L4, o = i / L4;
        const float* ip = h3 + (b * HD) * L3 + 2 * l;
        const float* wp = w4 + o * HD * 5;
        float acc = b4[o];
        #pragma unroll
        for (int ci = 0; ci < HD; ++ci)
            #pragma unroll
            for (int k = 0; k < 5; ++k)
                acc = fmaf(ip[ci * L3 + k], wp[ci * 5 + k], acc);
        sh4[i] = acc;
    }
    __syncthreads();

    if (tid < HD) {
        float s = 0.0f;
        for (int l = 0; l < L4; ++l) s += sh4[tid * L4 + l];
        hm[tid] = s * (1.0f / (float)L4);
    }
    __syncthreads();

    if (tid < CH * NM) {
        float acc = bl[tid];
        #pragma unroll
        for (int k = 0; k < HD; ++k) acc = fmaf(wl[tid * HD + k], hm[k], acc);
        sh4[tid] = acc;   // raw logits stash
    }
    __syncthreads();

    if (tid < CH) {
        float lv[NM];
        #pragma unroll
        for (int m = 0; m < NM; ++m) lv[m] = sh4[tid * NM + m];
        const float m0 = fmaxf(fmaxf(lv[0], lv[1]), fmaxf(lv[2], lv[3]));
        float e[NM], s = 0.0f;
        #pragma unroll
        for (int m = 0; m < NM; ++m) {
            const float v = (lv[m] - m0) / 0.1f;
            ltt[tid * NM + m] = v;
            e[m] = __expf(v);
            s += e[m];
        }
        #pragma unroll
        for (int m = 0; m < NM; ++m)
            out_mw[(b * CH + tid) * NM + m] = e[m] / s;
    }
    __syncthreads();

    for (int i = tid; i < NS * CH; i += 256) {
        const int c = i % CH, sI = i / CH;
        const float* up = unif + ((b * NS + sI) * CH + c) * NM;
        float hh[NM], mx = -1e30f;
        #pragma unroll
        for (int m = 0; m < NM; ++m) {
            const float gu = -__logf(-__logf(up[m] + 1e-8f));
            hh[m] = (gu + ltt[c * NM + m]) / 0.1f;
            mx = fmaxf(mx, hh[m]);
        }
        float e2[NM], ss = 0.0f;
        #pragma unroll
        for (int m = 0; m < NM; ++m) { e2[m] = __expf(hh[m] - mx); ss += e2[m]; }
        #pragma unroll
        for (int m = 0; m < NM; ++m) {
            float y = e2[m] / ss;
            y = fminf(fmaxf(y, 1e-8f), 1.0f - 1e-8f);
            out_ms[((b * NS + sI) * CH + c) * NM + m] = y;
        }
    }
}

// ---------------- fallback: fully fused net (round-3 proven) ----------------
__global__ __launch_bounds__(256) void k_net_fused(
    const float* __restrict__ rep,
    const float* __restrict__ w1, const float* __restrict__ b1,
    const float* __restrict__ w2, const float* __restrict__ b2,
    const float* __restrict__ w3, const float* __restrict__ b3,
    const float* __restrict__ w4, const float* __restrict__ b4,
    const float* __restrict__ wl, const float* __restrict__ bl,
    const float* __restrict__ unif,
    float* __restrict__ out_mw, float* __restrict__ out_ms)
{
    __shared__ float P[HD * L1];
    __shared__ float Q[HD * L2];
    __shared__ float hm[HD];
    __shared__ float lg[CH * NM];
    __shared__ float ltt[CH * NM];
    const int b   = blockIdx.x;
    const int tid = threadIdx.x;
    const float* repb = rep + b * G * CH;

    for (int i = tid; i < HD * L1; i += 256) {
        const int l = i % L1, o = i / L1;
        float acc = b1[o];
        for (int ci = 0; ci < CH; ++ci)
            #pragma unroll
            for (int k = 0; k < 5; ++k)
                acc = fmaf(repb[(2 * l + k) * CH + ci], w1[(o * CH + ci) * 5 + k], acc);
        P[i] = fmaxf(acc, 0.0f);
    }
    __syncthreads();
    for (int i = tid; i < HD * L2; i += 256) {
        const int l = i % L2, o = i / L2;
        float acc = b2[o];
        for (int ci = 0; ci < HD; ++ci)
            #pragma unroll
            for (int k = 0; k < 5; ++k)
                acc = fmaf(P[ci * L1 + 2 * l + k], w2[(o * HD + ci) * 5 + k], acc);
        Q[i] = fmaxf(acc, 0.0f);
    }
    __syncthreads();
    for (int i = tid; i < HD * L3; i += 256) {
        const int l = i % L3, o = i / L3;
        float acc = b3[o];
        for (int ci = 0; ci < HD; ++ci)
            #pragma unroll
            for (int k = 0; k < 5; ++k)
                acc = fmaf(Q[ci * L2 + 2 * l + k], w3[(o * HD + ci) * 5 + k], acc);
        P[i] = fmaxf(acc, 0.0f);
    }
    __syncthreads();
    for (int i = tid; i < HD * L4; i += 256) {
        const int l = i % L4, o = i / L4;
        float acc = b4[o];
        for (int ci = 0; ci < HD; ++ci)
            #pragma unroll
            for (int k = 0; k < 5; ++k)
                acc = fmaf(P[ci * L3 + 2 * l + k], w4[(o * HD + ci) * 5 + k], acc);
        Q[i] = acc;
    }
    __syncthreads();
    if (tid < HD) {
        float s = 0.0f;
        for (int l = 0; l < L4; ++l) s += Q[tid * L4 + l];
        hm[tid] = s * (1.0f / (float)L4);
    }
    __syncthreads();
    if (tid < CH * NM) {
        float acc = bl[tid];
        #pragma unroll
        for (int k = 0; k < HD; ++k) acc = fmaf(wl[tid * HD + k], hm[k], acc);
        lg[tid] = acc;
    }
    __syncthreads();
    if (tid < CH) {
        float lv[NM];
        #pragma unroll
        for (int m = 0; m < NM; ++m) lv[m] = lg[tid * NM + m];
        const float m0 = fmaxf(fmaxf(lv[0], lv[1]), fmaxf(lv[2], lv[3]));
        float e[NM], s = 0.0f;
        #pragma unroll
        for (int m = 0; m < NM; ++m) {
            const float v = (lv[m] - m0) / 0.1f;
            ltt[tid * NM + m] = v;
            e[m] = __expf(v);
            s += e[m];
        }
        #pragma unroll
        for (int m = 0; m < NM; ++m)
            out_mw[(b * CH + tid) * NM + m] = e[m] / s;
    }
    __syncthreads();
    for (int i = tid; i < NS * CH; i += 256) {
        const int c = i % CH, sI = i / CH;
        const float* up = unif + ((b * NS + sI) * CH + c) * NM;
        float hh[NM], mx = -1e30f;
        #pragma unroll
        for (int m = 0; m < NM; ++m) {
            const float gu = -__logf(-__logf(up[m] + 1e-8f));
            hh[m] = (gu + ltt[c * NM + m]) / 0.1f;
            mx = fmaxf(mx, hh[m]);
        }
        float e2[NM], ss = 0.0f;
        #pragma unroll
        for (int m = 0; m < NM; ++m) { e2[m] = __expf(hh[m] - mx); ss += e2[m]; }
        #pragma unroll
        for (int m = 0; m < NM; ++m) {
            float y = e2[m] / ss;
            y = fminf(fmaxf(y, 1e-8f), 1.0f - 1e-8f);
            out_ms[((b * NS + sI) * CH + c) * NM + m] = y;
        }
    }
}

extern "C" void kernel_launch(void* const* d_in, const int* in_sizes, int n_in,
                              void* d_out, int out_size, void* d_ws, size_t ws_size,
                              hipStream_t stream) {
    const float* xc    = (const float*)d_in[0];
    const float* yc    = (const float*)d_in[1];
    const float* xg    = (const float*)d_in[2];
    const float* logls = (const float*)d_in[3];
    const float* w1    = (const float*)d_in[4];
    const float* b1    = (const float*)d_in[5];
    const float* w2    = (const float*)d_in[6];
    const float* b2    = (const float*)d_in[7];
    const float* w3    = (const float*)d_in[8];
    const float* b3    = (const float*)d_in[9];
    const float* w4    = (const float*)d_in[10];
    const float* b4    = (const float*)d_in[11];
    const float* wl    = (const float*)d_in[12];
    const float* bl    = (const float*)d_in[13];
    const float* unif  = (const float*)d_in[14];

    float* out = (float*)d_out;                 // reference outputs are float32
    float* out_den = out;                       // 131072
    float* out_rep = out + NB * G * CH;         // 131072
    float* out_mw  = out + 2 * NB * G * CH;     // 256
    float* out_ms  = out_mw + NB * CH * NM;     // 2560
    (void)out_size; (void)in_sizes; (void)n_in;

    k_density<<<NB * 64, 256, 0, stream>>>(xc, yc, xg, logls, out_den, out_rep);

    const size_t ws_need = (size_t)(NB * HD * (L1 + L2 + L3)) * sizeof(float); // 570,880 B
    if (ws_size >= ws_need) {
        float* ws_h1 = (float*)d_ws;                 // NB*HD*L1 = 81760
        float* ws_h2 = ws_h1 + NB * HD * L1;         // NB*HD*L2 = 40720
        float* ws_h3 = ws_h2 + NB * HD * L2;         // NB*HD*L3 = 20240

        k_conv1<<<(NB * HD * L1 + 255) / 256, 256, 0, stream>>>(out_rep, w1, b1, ws_h1);
        k_conv<HD, L1, L2><<<(NB * HD * L2 + 255) / 256, 256, 0, stream>>>(ws_h1, w2, b2, ws_h2);
        k_conv<HD, L2, L3><<<(NB * HD * L3 + 255) / 256, 256, 0, stream>>>(ws_h2, w3, b3, ws_h3);
        k_head<<<NB, 256, 0, stream>>>(ws_h3, w4, b4, wl, bl, unif, out_mw, out_ms);
    } else {
        k_net_fused<<<NB, 256, 0, stream>>>(out_rep, w1, b1, w2, b2, w3, b3, w4, b4,
                                            wl, bl, unif, out_mw, out_ms);
    }
}